// Round 10
// baseline (215.261 us; speedup 1.0000x reference)
//
#include <hip/hip_runtime.h>
#include <math.h>

// Problem constants
#define B 512
#define E 256
#define L 1024  // 32*32

typedef float f32x4 __attribute__((ext_vector_type(4)));
typedef unsigned long long u64;

// Workspace layout (floats)
#define O_Q     0u           // B*L   raw_q
#define O_SOMN  524288u      // L*E
#define O_PART  786432u      // 16*L  colsum partials
#define O_PRS   802816u      // 16*B  rowsum partials (from distq)
#define O_H     811008u      // B*L   eta-scaled h
#define O_BMUP  1335296u     // 16*B u64 packed per-tile argmin candidates

// ---------------------------------------------------------------------------
// K1: dist^2(Z, SOM) fused argmin -> bmupart[tn][b] = (bits(d2)<<32)|j (packed).
// ---------------------------------------------------------------------------
__global__ __launch_bounds__(256) void dist_bmu_kernel(const float* __restrict__ Zg,
                                                       const float* __restrict__ Wg,
                                                       u64* __restrict__ bmupart) {
    __shared__ float Zs[64][67];
    __shared__ float Ws[64][67];
    __shared__ u64 red[64][16];
    const int tid = threadIdx.x;
    const int tb = blockIdx.x >> 4;   // 0..7
    const int tn = blockIdx.x & 15;   // 0..15
    const int b0 = tb * 64, n0 = tn * 64;
    const int ty = tid >> 4, tx = tid & 15;

    float acc[4][4];
#pragma unroll
    for (int i = 0; i < 4; ++i)
#pragma unroll
        for (int j = 0; j < 4; ++j) acc[i][j] = 0.f;

    for (int kc = 0; kc < E; kc += 64) {
        const int c4 = tx * 4;
#pragma unroll
        for (int s = 0; s < 4; ++s) {
            const int r = ty + 16 * s;
            float4 zv = *(const float4*)(Zg + (size_t)(b0 + r) * E + kc + c4);
            Zs[r][c4 + 0] = zv.x; Zs[r][c4 + 1] = zv.y;
            Zs[r][c4 + 2] = zv.z; Zs[r][c4 + 3] = zv.w;
            float4 wv = *(const float4*)(Wg + (size_t)(n0 + r) * E + kc + c4);
            Ws[r][c4 + 0] = wv.x; Ws[r][c4 + 1] = wv.y;
            Ws[r][c4 + 2] = wv.z; Ws[r][c4 + 3] = wv.w;
        }
        __syncthreads();
#pragma unroll 4
        for (int k = 0; k < 64; ++k) {
            float zr[4], wr[4];
#pragma unroll
            for (int i = 0; i < 4; ++i) zr[i] = Zs[ty * 4 + i][k];
#pragma unroll
            for (int j = 0; j < 4; ++j) wr[j] = Ws[tx * 4 + j][k];
#pragma unroll
            for (int i = 0; i < 4; ++i)
#pragma unroll
                for (int j = 0; j < 4; ++j) {
                    float d = zr[i] - wr[j];
                    acc[i][j] = fmaf(d, d, acc[i][j]);
                }
        }
        __syncthreads();
    }
#pragma unroll
    for (int i = 0; i < 4; ++i) {
        float best = acc[i][0];
        int bj = 0;
#pragma unroll
        for (int j = 1; j < 4; ++j)
            if (acc[i][j] < best) { best = acc[i][j]; bj = j; }
        red[ty * 4 + i][tx] = ((u64)__float_as_uint(best) << 32) |
                              (unsigned)(n0 + tx * 4 + bj);
    }
    __syncthreads();
    if (tid < 64) {
        u64 m = red[tid][0];
#pragma unroll
        for (int t = 1; t < 16; ++t) {
            const u64 v = red[tid][t];
            if (v < m) m = v;
        }
        bmupart[(size_t)tn * B + b0 + tid] = m;
    }
}

// K2: reduce bmu candidates + h[b, hw] = eta * exp(-lattice_d2 / (2 sigma^2))
__global__ __launch_bounds__(256) void h_kernel(const u64* __restrict__ bmupart,
                                                const int* __restrict__ step,
                                                float* __restrict__ h) {
    const int b = blockIdx.x;
    u64 m = bmupart[b];
#pragma unroll
    for (int tn = 1; tn < 16; ++tn) {
        const u64 v = bmupart[(size_t)tn * B + b];
        if (v < m) m = v;
    }
    const int u = (int)(m & 0xffffffffULL);
    const int ur = u >> 5, uc = u & 31;
    const float n = (float)step[0];
    const float decay = expf(-n * 0.01f);
    const float eta = 0.3f * decay;
    const float sigma = 16.0f * decay;
    const float inv2s2 = 1.0f / (2.0f * sigma * sigma);
#pragma unroll
    for (int s = 0; s < 4; ++s) {
        const int t = threadIdx.x + s * 256;
        const int i = t >> 5, j = t & 31;
        const float dr = (float)(ur - i), dc = (float)(uc - j);
        h[(size_t)b * L + t] = eta * expf(-(dr * dr + dc * dc) * inv2s2);
    }
}

// K3: SOM_new[hw,e] = SOM + (1/B)*(sum_b h*Z - (sum_b h)*SOM)  (R5-proven form)
__global__ __launch_bounds__(256) void update_kernel(const float* __restrict__ Zg,
                                                     const float* __restrict__ Wg,
                                                     const float* __restrict__ h,
                                                     float* __restrict__ somn) {
    const int hw = blockIdx.x;
    const int e = threadIdx.x;
    float acc = 0.f, hsum = 0.f;
#pragma unroll 8
    for (int b = 0; b < B; ++b) {
        const float hv = h[(size_t)b * L + hw];
        acc = fmaf(hv, Zg[(size_t)b * E + e], acc);
        hsum += hv;
    }
    const float w = Wg[(size_t)hw * E + e];
    somn[(size_t)hw * E + e] = w + (1.0f / (float)B) * (acc - hsum * w);
}

// ---------------------------------------------------------------------------
// K4: delta[b, hw, e] = h[b,hw] * (Z[b,e] - SOM[hw,e]) — the 537 MB writer.
// Fill-mimic: stage W/Z/h chunk in LDS, then pure {ds_read -> VALU -> plain
// dwordx4 store} stream. Zero global reads during the write stream => plain
// stores can use L2 write-back at fill's 6.6 TB/s without read-thrash.
// Block: 16 b x 32 hw, 50 KB LDS, 512 thr (2 blocks/CU). 1024 blocks.
// ---------------------------------------------------------------------------
#define BCH 16
#define HCH 32
__global__ __launch_bounds__(512) void delta_lds_kernel(const float* __restrict__ Zg,
                                                        const float* __restrict__ Wg,
                                                        const float* __restrict__ h,
                                                        float* __restrict__ delta) {
    __shared__ float Ws_l[HCH * E];   // 32 KB
    __shared__ float Zs_l[BCH * E];   // 16 KB
    __shared__ float hs_l[BCH * HCH]; //  2 KB
    const int tid = threadIdx.x;
    const int bc = blockIdx.x >> 5;   // 0..31
    const int hc = blockIdx.x & 31;   // 0..31
    const int b0 = bc * BCH, hw0 = hc * HCH;

    // stage W chunk (8192 floats, 4 passes of 512 x float4)
    {
        const float* src = Wg + (size_t)hw0 * E;
#pragma unroll
        for (int p = 0; p < 4; ++p) {
            const int o = (p * 512 + tid) * 4;
            *(float4*)(Ws_l + o) = *(const float4*)(src + o);
        }
        const float* zsrc = Zg + (size_t)b0 * E;
#pragma unroll
        for (int p = 0; p < 2; ++p) {
            const int o = (p * 512 + tid) * 4;
            *(float4*)(Zs_l + o) = *(const float4*)(zsrc + o);
        }
        const int i = tid >> 5, j = tid & 31;   // 512 floats, one pass
        hs_l[tid] = h[(size_t)(b0 + i) * L + hw0 + j];
    }
    __syncthreads();

    const int wid = tid >> 6;      // 0..7
    const int lane = tid & 63;
    const int r0 = wid * 4;        // 4 rows per wave per b (32 rows / 8 waves)
    for (int i = 0; i < BCH; ++i) {
        const float4 z = *(const float4*)(Zs_l + i * E + lane * 4);
        float* drow = delta + ((size_t)(b0 + i) * L + hw0 + r0) * E + lane * 4;
#pragma unroll
        for (int r = 0; r < 4; ++r) {
            const float hs = hs_l[i * HCH + r0 + r];          // uniform broadcast
            const float4 w = *(const float4*)(Ws_l + (r0 + r) * E + lane * 4);
            f32x4 o;
            o.x = hs * (z.x - w.x);
            o.y = hs * (z.y - w.y);
            o.z = hs * (z.z - w.z);
            o.w = hs * (z.w - w.w);
            *(f32x4*)(drow + (size_t)r * E) = o;              // plain cached store
        }
    }
}

// ---------------------------------------------------------------------------
// K5: raw_q = 1/(1+dist(Z, SOM_new)) + fixed-order per-block row partials
// ---------------------------------------------------------------------------
__global__ __launch_bounds__(256) void distq_kernel(const float* __restrict__ Zg,
                                                    const float* __restrict__ Wg,
                                                    float* __restrict__ out,
                                                    float* __restrict__ part_rs) {
    __shared__ float Zs[64][67];
    __shared__ float Ws[64][67];
    __shared__ float red[64][16];
    const int tid = threadIdx.x;
    const int tb = blockIdx.x >> 4;
    const int tn = blockIdx.x & 15;
    const int b0 = tb * 64, n0 = tn * 64;
    const int ty = tid >> 4, tx = tid & 15;

    float acc[4][4];
#pragma unroll
    for (int i = 0; i < 4; ++i)
#pragma unroll
        for (int j = 0; j < 4; ++j) acc[i][j] = 0.f;

    for (int kc = 0; kc < E; kc += 64) {
        const int c4 = tx * 4;
#pragma unroll
        for (int s = 0; s < 4; ++s) {
            const int r = ty + 16 * s;
            float4 zv = *(const float4*)(Zg + (size_t)(b0 + r) * E + kc + c4);
            Zs[r][c4 + 0] = zv.x; Zs[r][c4 + 1] = zv.y;
            Zs[r][c4 + 2] = zv.z; Zs[r][c4 + 3] = zv.w;
            float4 wv = *(const float4*)(Wg + (size_t)(n0 + r) * E + kc + c4);
            Ws[r][c4 + 0] = wv.x; Ws[r][c4 + 1] = wv.y;
            Ws[r][c4 + 2] = wv.z; Ws[r][c4 + 3] = wv.w;
        }
        __syncthreads();
#pragma unroll 4
        for (int k = 0; k < 64; ++k) {
            float zr[4], wr[4];
#pragma unroll
            for (int i = 0; i < 4; ++i) zr[i] = Zs[ty * 4 + i][k];
#pragma unroll
            for (int j = 0; j < 4; ++j) wr[j] = Ws[tx * 4 + j][k];
#pragma unroll
            for (int i = 0; i < 4; ++i)
#pragma unroll
                for (int j = 0; j < 4; ++j) {
                    float d = zr[i] - wr[j];
                    acc[i][j] = fmaf(d, d, acc[i][j]);
                }
        }
        __syncthreads();
    }
#pragma unroll
    for (int i = 0; i < 4; ++i) {
        const int b = b0 + ty * 4 + i;
        float4 v;
        v.x = 1.f / (1.f + sqrtf(acc[i][0]));
        v.y = 1.f / (1.f + sqrtf(acc[i][1]));
        v.z = 1.f / (1.f + sqrtf(acc[i][2]));
        v.w = 1.f / (1.f + sqrtf(acc[i][3]));
        *(float4*)(out + (size_t)b * L + n0 + tx * 4) = v;
        red[ty * 4 + i][tx] = v.x + v.y + v.z + v.w;   // fixed order within thread
    }
    __syncthreads();
    if (tid < 64) {
        float s = red[tid][0];
#pragma unroll
        for (int t = 1; t < 16; ++t) s += red[tid][t];  // ascending tx = ascending j
        part_rs[(size_t)tn * B + b0 + tid] = s;
    }
}

// K6: colsum partials with inline irs: part[c][j] = sum_{b in chunk} q[b][j]*irs[b]
__global__ __launch_bounds__(256) void colsum_part_kernel(const float* __restrict__ q,
                                                          const float* __restrict__ prs,
                                                          float* __restrict__ part) {
    __shared__ float sirs[32];
    const int j = (blockIdx.x & 3) * 256 + threadIdx.x;
    const int c = blockIdx.x >> 2;   // 0..15
    const int b0 = c * 32;
    if (threadIdx.x < 32) {
        float s = 0.f;
#pragma unroll
        for (int tn = 0; tn < 16; ++tn) s += prs[(size_t)tn * B + b0 + threadIdx.x];
        sirs[threadIdx.x] = 1.0f / s;
    }
    __syncthreads();
    float acc = 0.f;
#pragma unroll 8
    for (int bo = 0; bo < 32; ++bo)
        acc = fmaf(q[(size_t)(b0 + bo) * L + j], sirs[bo], acc);
    part[(size_t)c * L + j] = acc;
}

// K7: kl[b] = T/S - log(S); irs[b] and cs[j] computed inline (fixed order).
__global__ __launch_bounds__(256) void kl_kernel(const float* __restrict__ q,
                                                 const float* __restrict__ prs,
                                                 const float* __restrict__ part,
                                                 float* __restrict__ kl) {
    const int b = blockIdx.x;
    const int tid = threadIdx.x;
    float rs = 0.f;
#pragma unroll
    for (int tn = 0; tn < 16; ++tn) rs += prs[(size_t)tn * B + b];  // uniform -> broadcast
    const float irsb = 1.0f / rs;
    float S = 0.f, T = 0.f;
#pragma unroll
    for (int s = 0; s < 4; ++s) {
        const int j = tid + s * 256;
        float csj = 0.f;
#pragma unroll
        for (int c = 0; c < 16; ++c) csj += part[(size_t)c * L + j];
        const float qq = q[(size_t)b * L + j] * irsb;
        const float ic = 1.0f / csj;
        const float rp = qq * qq * ic;
        S += rp;
        T = fmaf(rp, logf(qq * ic), T);
    }
    __shared__ float sS[256], sT[256];
    sS[tid] = S; sT[tid] = T;
    __syncthreads();
    for (int st = 128; st > 0; st >>= 1) {
        if (tid < st) { sS[tid] += sS[tid + st]; sT[tid] += sT[tid + st]; }
        __syncthreads();
    }
    if (tid == 0) kl[b] = sT[0] / sS[0] - logf(sS[0]);
}

extern "C" void kernel_launch(void* const* d_in, const int* in_sizes, int n_in,
                              void* d_out, int out_size, void* d_ws, size_t ws_size,
                              hipStream_t stream) {
    const float* Zg = (const float*)d_in[0];
    const float* Wg = (const float*)d_in[1];
    const int* step = (const int*)d_in[2];
    float* out = (float*)d_out;          // [0,512): kl_loss, [512,...): delta
    float* ws = (float*)d_ws;

    float* q    = ws + O_Q;
    float* somn = ws + O_SOMN;
    float* part = ws + O_PART;
    float* prs  = ws + O_PRS;
    float* h    = ws + O_H;
    u64*   bmup = (u64*)(ws + O_BMUP);

    float* kl    = out;
    float* delta = out + B;

    hipLaunchKernelGGL(dist_bmu_kernel, dim3(128), dim3(256), 0, stream, Zg, Wg, bmup);
    hipLaunchKernelGGL(h_kernel, dim3(B), dim3(256), 0, stream, bmup, step, h);
    hipLaunchKernelGGL(update_kernel, dim3(L), dim3(256), 0, stream, Zg, Wg, h, somn);
    hipLaunchKernelGGL(delta_lds_kernel, dim3(1024), dim3(512), 0, stream, Zg, Wg, h, delta);
    hipLaunchKernelGGL(distq_kernel, dim3(128), dim3(256), 0, stream, Zg, somn, q, prs);
    hipLaunchKernelGGL(colsum_part_kernel, dim3(64), dim3(256), 0, stream, q, prs, part);
    hipLaunchKernelGGL(kl_kernel, dim3(B), dim3(256), 0, stream, q, prs, part, kl);
}

// Round 11
// 174.723 us; speedup vs baseline: 1.2320x; 1.2320x over previous
//
#include <hip/hip_runtime.h>
#include <math.h>

// Problem constants
#define B 512
#define E 256
#define L 1024  // 32*32

typedef float f32x4 __attribute__((ext_vector_type(4)));
typedef unsigned long long u64;

// Workspace layout (floats)
#define O_Q     0u           // B*L   raw_q
#define O_SOMN  524288u      // L*E
#define O_PRS   786432u      // 16*B  rowsum partials (from distq)
#define O_H     794624u      // B*L   eta-scaled h
#define O_BMUP  1318912u     // 16*B u64 packed per-tile argmin candidates

// ---------------------------------------------------------------------------
// K1: dist^2(Z, SOM) fused argmin -> bmupart[tn][b] = (bits(d2)<<32)|j (packed).
// ---------------------------------------------------------------------------
__global__ __launch_bounds__(256) void dist_bmu_kernel(const float* __restrict__ Zg,
                                                       const float* __restrict__ Wg,
                                                       u64* __restrict__ bmupart) {
    __shared__ float Zs[64][67];
    __shared__ float Ws[64][67];
    __shared__ u64 red[64][16];
    const int tid = threadIdx.x;
    const int tb = blockIdx.x >> 4;   // 0..7
    const int tn = blockIdx.x & 15;   // 0..15
    const int b0 = tb * 64, n0 = tn * 64;
    const int ty = tid >> 4, tx = tid & 15;

    float acc[4][4];
#pragma unroll
    for (int i = 0; i < 4; ++i)
#pragma unroll
        for (int j = 0; j < 4; ++j) acc[i][j] = 0.f;

    for (int kc = 0; kc < E; kc += 64) {
        const int c4 = tx * 4;
#pragma unroll
        for (int s = 0; s < 4; ++s) {
            const int r = ty + 16 * s;
            float4 zv = *(const float4*)(Zg + (size_t)(b0 + r) * E + kc + c4);
            Zs[r][c4 + 0] = zv.x; Zs[r][c4 + 1] = zv.y;
            Zs[r][c4 + 2] = zv.z; Zs[r][c4 + 3] = zv.w;
            float4 wv = *(const float4*)(Wg + (size_t)(n0 + r) * E + kc + c4);
            Ws[r][c4 + 0] = wv.x; Ws[r][c4 + 1] = wv.y;
            Ws[r][c4 + 2] = wv.z; Ws[r][c4 + 3] = wv.w;
        }
        __syncthreads();
#pragma unroll 4
        for (int k = 0; k < 64; ++k) {
            float zr[4], wr[4];
#pragma unroll
            for (int i = 0; i < 4; ++i) zr[i] = Zs[ty * 4 + i][k];
#pragma unroll
            for (int j = 0; j < 4; ++j) wr[j] = Ws[tx * 4 + j][k];
#pragma unroll
            for (int i = 0; i < 4; ++i)
#pragma unroll
                for (int j = 0; j < 4; ++j) {
                    float d = zr[i] - wr[j];
                    acc[i][j] = fmaf(d, d, acc[i][j]);
                }
        }
        __syncthreads();
    }
#pragma unroll
    for (int i = 0; i < 4; ++i) {
        float best = acc[i][0];
        int bj = 0;
#pragma unroll
        for (int j = 1; j < 4; ++j)
            if (acc[i][j] < best) { best = acc[i][j]; bj = j; }
        red[ty * 4 + i][tx] = ((u64)__float_as_uint(best) << 32) |
                              (unsigned)(n0 + tx * 4 + bj);
    }
    __syncthreads();
    if (tid < 64) {
        u64 m = red[tid][0];
#pragma unroll
        for (int t = 1; t < 16; ++t) {
            const u64 v = red[tid][t];
            if (v < m) m = v;
        }
        bmupart[(size_t)tn * B + b0 + tid] = m;
    }
}

// K2: reduce bmu candidates + h[b, hw] = eta * exp(-lattice_d2 / (2 sigma^2))
__global__ __launch_bounds__(256) void h_kernel(const u64* __restrict__ bmupart,
                                                const int* __restrict__ step,
                                                float* __restrict__ h) {
    const int b = blockIdx.x;
    u64 m = bmupart[b];
#pragma unroll
    for (int tn = 1; tn < 16; ++tn) {
        const u64 v = bmupart[(size_t)tn * B + b];
        if (v < m) m = v;
    }
    const int u = (int)(m & 0xffffffffULL);
    const int ur = u >> 5, uc = u & 31;
    const float n = (float)step[0];
    const float decay = expf(-n * 0.01f);
    const float eta = 0.3f * decay;
    const float sigma = 16.0f * decay;
    const float inv2s2 = 1.0f / (2.0f * sigma * sigma);
#pragma unroll
    for (int s = 0; s < 4; ++s) {
        const int t = threadIdx.x + s * 256;
        const int i = t >> 5, j = t & 31;
        const float dr = (float)(ur - i), dc = (float)(uc - j);
        h[(size_t)b * L + t] = eta * expf(-(dr * dr + dc * dc) * inv2s2);
    }
}

// ---------------------------------------------------------------------------
// K3 mega1: blocks 0..1023 -> SOM update; blocks 1024.. -> delta for b in [0,256).
// Delta per-thread code is the R5/R8-proven one-NT-store form.
// ---------------------------------------------------------------------------
__global__ __launch_bounds__(256) void delta_update_kernel(const float* __restrict__ Zg,
                                                           const float* __restrict__ Wg,
                                                           const float* __restrict__ h,
                                                           float* __restrict__ somn,
                                                           float* __restrict__ delta) {
    if (blockIdx.x < 1024) {
        const int hw = blockIdx.x;
        const int e = threadIdx.x;
        float acc = 0.f, hsum = 0.f;
#pragma unroll 8
        for (int b = 0; b < B; ++b) {
            const float hv = h[(size_t)b * L + hw];
            acc = fmaf(hv, Zg[(size_t)b * E + e], acc);
            hsum += hv;
        }
        const float w = Wg[(size_t)hw * E + e];
        somn[(size_t)hw * E + e] = w + (1.0f / (float)B) * (acc - hsum * w);
        return;
    }
    const int bid = blockIdx.x - 1024;       // 256 b * 256 blocks
    const int b = bid >> 8;                  // 0..255
    const int hw = ((bid & 255) << 2) + (threadIdx.x >> 6);
    const int lane = threadIdx.x & 63;
    const float hs = h[(size_t)b * L + hw];
    const float4 z = *(const float4*)(Zg + (size_t)b * E + lane * 4);
    const float4 w = *(const float4*)(Wg + (size_t)hw * E + lane * 4);
    f32x4 o;
    o.x = hs * (z.x - w.x);
    o.y = hs * (z.y - w.y);
    o.z = hs * (z.z - w.z);
    o.w = hs * (z.w - w.w);
    __builtin_nontemporal_store(o, (f32x4*)(delta + ((size_t)b * L + hw) * E + lane * 4));
}

// ---------------------------------------------------------------------------
// K4: raw_q = 1/(1+dist(Z, SOM_new)) + fixed-order per-block row partials
// ---------------------------------------------------------------------------
__global__ __launch_bounds__(256) void distq_kernel(const float* __restrict__ Zg,
                                                    const float* __restrict__ Wg,
                                                    float* __restrict__ out,
                                                    float* __restrict__ part_rs) {
    __shared__ float Zs[64][67];
    __shared__ float Ws[64][67];
    __shared__ float red[64][16];
    const int tid = threadIdx.x;
    const int tb = blockIdx.x >> 4;
    const int tn = blockIdx.x & 15;
    const int b0 = tb * 64, n0 = tn * 64;
    const int ty = tid >> 4, tx = tid & 15;

    float acc[4][4];
#pragma unroll
    for (int i = 0; i < 4; ++i)
#pragma unroll
        for (int j = 0; j < 4; ++j) acc[i][j] = 0.f;

    for (int kc = 0; kc < E; kc += 64) {
        const int c4 = tx * 4;
#pragma unroll
        for (int s = 0; s < 4; ++s) {
            const int r = ty + 16 * s;
            float4 zv = *(const float4*)(Zg + (size_t)(b0 + r) * E + kc + c4);
            Zs[r][c4 + 0] = zv.x; Zs[r][c4 + 1] = zv.y;
            Zs[r][c4 + 2] = zv.z; Zs[r][c4 + 3] = zv.w;
            float4 wv = *(const float4*)(Wg + (size_t)(n0 + r) * E + kc + c4);
            Ws[r][c4 + 0] = wv.x; Ws[r][c4 + 1] = wv.y;
            Ws[r][c4 + 2] = wv.z; Ws[r][c4 + 3] = wv.w;
        }
        __syncthreads();
#pragma unroll 4
        for (int k = 0; k < 64; ++k) {
            float zr[4], wr[4];
#pragma unroll
            for (int i = 0; i < 4; ++i) zr[i] = Zs[ty * 4 + i][k];
#pragma unroll
            for (int j = 0; j < 4; ++j) wr[j] = Ws[tx * 4 + j][k];
#pragma unroll
            for (int i = 0; i < 4; ++i)
#pragma unroll
                for (int j = 0; j < 4; ++j) {
                    float d = zr[i] - wr[j];
                    acc[i][j] = fmaf(d, d, acc[i][j]);
                }
        }
        __syncthreads();
    }
#pragma unroll
    for (int i = 0; i < 4; ++i) {
        const int b = b0 + ty * 4 + i;
        float4 v;
        v.x = 1.f / (1.f + sqrtf(acc[i][0]));
        v.y = 1.f / (1.f + sqrtf(acc[i][1]));
        v.z = 1.f / (1.f + sqrtf(acc[i][2]));
        v.w = 1.f / (1.f + sqrtf(acc[i][3]));
        *(float4*)(out + (size_t)b * L + n0 + tx * 4) = v;
        red[ty * 4 + i][tx] = v.x + v.y + v.z + v.w;   // fixed order within thread
    }
    __syncthreads();
    if (tid < 64) {
        float s = red[tid][0];
#pragma unroll
        for (int t = 1; t < 16; ++t) s += red[tid][t];  // ascending tx = ascending j
        part_rs[(size_t)tn * B + b0 + tid] = s;
    }
}

// ---------------------------------------------------------------------------
// K5 mega2: blocks 0..511 -> KL (with inline colsum); blocks 512.. -> delta
// for b in [256,512). KL block b: stage irs[512] in LDS, each thread owns 4
// consecutive j, accumulates cs[j] over all b (fixed ascending order), then
// computes S,T and tree-reduces. ~3 µs each, hidden under the delta stream.
// ---------------------------------------------------------------------------
__global__ __launch_bounds__(256) void delta_kl_kernel(const float* __restrict__ Zg,
                                                       const float* __restrict__ Wg,
                                                       const float* __restrict__ h,
                                                       const float* __restrict__ q,
                                                       const float* __restrict__ prs,
                                                       float* __restrict__ kl,
                                                       float* __restrict__ delta) {
    if (blockIdx.x < 512) {
        __shared__ float sirs[B];
        __shared__ float sS[256], sT[256];
        const int tid = threadIdx.x;
#pragma unroll
        for (int s = 0; s < 2; ++s) {
            const int bb = tid + s * 256;
            float ss = 0.f;
#pragma unroll
            for (int tn = 0; tn < 16; ++tn) ss += prs[(size_t)tn * B + bb];
            sirs[bb] = 1.0f / ss;
        }
        __syncthreads();

        const int j4 = tid * 4;
        float cs0 = 0.f, cs1 = 0.f, cs2 = 0.f, cs3 = 0.f;
#pragma unroll 8
        for (int b = 0; b < B; ++b) {
            const float4 qv = *(const float4*)(q + (size_t)b * L + j4);
            const float ir = sirs[b];
            cs0 = fmaf(qv.x, ir, cs0);
            cs1 = fmaf(qv.y, ir, cs1);
            cs2 = fmaf(qv.z, ir, cs2);
            cs3 = fmaf(qv.w, ir, cs3);
        }
        const int bq = blockIdx.x;
        const float irsb = sirs[bq];
        const float4 qb = *(const float4*)(q + (size_t)bq * L + j4);
        float S = 0.f, T = 0.f;
        {
            const float qq = qb.x * irsb, ic = 1.0f / cs0;
            const float rp = qq * qq * ic;
            S += rp; T = fmaf(rp, logf(qq * ic), T);
        }
        {
            const float qq = qb.y * irsb, ic = 1.0f / cs1;
            const float rp = qq * qq * ic;
            S += rp; T = fmaf(rp, logf(qq * ic), T);
        }
        {
            const float qq = qb.z * irsb, ic = 1.0f / cs2;
            const float rp = qq * qq * ic;
            S += rp; T = fmaf(rp, logf(qq * ic), T);
        }
        {
            const float qq = qb.w * irsb, ic = 1.0f / cs3;
            const float rp = qq * qq * ic;
            S += rp; T = fmaf(rp, logf(qq * ic), T);
        }
        sS[tid] = S; sT[tid] = T;
        __syncthreads();
        for (int st = 128; st > 0; st >>= 1) {
            if (tid < st) { sS[tid] += sS[tid + st]; sT[tid] += sT[tid + st]; }
            __syncthreads();
        }
        if (tid == 0) kl[bq] = sT[0] / sS[0] - logf(sS[0]);
        return;
    }
    // --- delta path, b in [256, 512)
    const int bid = blockIdx.x - 512;        // 256 b * 256 blocks
    const int b = 256 + (bid >> 8);
    const int hw = ((bid & 255) << 2) + (threadIdx.x >> 6);
    const int lane = threadIdx.x & 63;
    const float hs = h[(size_t)b * L + hw];
    const float4 z = *(const float4*)(Zg + (size_t)b * E + lane * 4);
    const float4 w = *(const float4*)(Wg + (size_t)hw * E + lane * 4);
    f32x4 o;
    o.x = hs * (z.x - w.x);
    o.y = hs * (z.y - w.y);
    o.z = hs * (z.z - w.z);
    o.w = hs * (z.w - w.w);
    __builtin_nontemporal_store(o, (f32x4*)(delta + ((size_t)b * L + hw) * E + lane * 4));
}

extern "C" void kernel_launch(void* const* d_in, const int* in_sizes, int n_in,
                              void* d_out, int out_size, void* d_ws, size_t ws_size,
                              hipStream_t stream) {
    const float* Zg = (const float*)d_in[0];
    const float* Wg = (const float*)d_in[1];
    const int* step = (const int*)d_in[2];
    float* out = (float*)d_out;          // [0,512): kl_loss, [512,...): delta
    float* ws = (float*)d_ws;

    float* q    = ws + O_Q;
    float* somn = ws + O_SOMN;
    float* prs  = ws + O_PRS;
    float* h    = ws + O_H;
    u64*   bmup = (u64*)(ws + O_BMUP);

    float* kl    = out;
    float* delta = out + B;

    hipLaunchKernelGGL(dist_bmu_kernel, dim3(128), dim3(256), 0, stream, Zg, Wg, bmup);
    hipLaunchKernelGGL(h_kernel, dim3(B), dim3(256), 0, stream, bmup, step, h);
    hipLaunchKernelGGL(delta_update_kernel, dim3(1024 + 256 * 256), dim3(256), 0, stream,
                       Zg, Wg, h, somn, delta);
    hipLaunchKernelGGL(distq_kernel, dim3(128), dim3(256), 0, stream, Zg, somn, q, prs);
    hipLaunchKernelGGL(delta_kl_kernel, dim3(512 + 256 * 256), dim3(256), 0, stream,
                       Zg, Wg, h, q, prs, kl, delta);
}

// Round 12
// 132.868 us; speedup vs baseline: 1.6201x; 1.3150x over previous
//
#include <hip/hip_runtime.h>
#include <math.h>

// Problem constants
#define B 512
#define E 256
#define L 1024  // 32*32

typedef float f32x4 __attribute__((ext_vector_type(4)));
typedef unsigned long long u64;

// Workspace layout (floats)
#define O_Q     0u           // B*L   raw_q
#define O_SOMN  524288u      // L*E
#define O_PART  786432u      // 16*L  colsum partials
#define O_PRS   802816u      // 16*B  rowsum partials (from distq)
#define O_H     811008u      // B*L   eta-scaled h
#define O_BMUP  1335296u     // 16*B u64 packed per-tile argmin candidates

// ---------------------------------------------------------------------------
// K1: dist^2(Z, SOM) fused argmin -> bmupart[tn][b] = (bits(d2)<<32)|j.
// 32(b) x 64(j) tiles -> 256 blocks (full 256-CU coverage; R8's 128-block
// version left half the GPU idle). Same per-output summation order.
// ---------------------------------------------------------------------------
__global__ __launch_bounds__(256) void dist_bmu_kernel(const float* __restrict__ Zg,
                                                       const float* __restrict__ Wg,
                                                       u64* __restrict__ bmupart) {
    __shared__ float Zs[32][67];
    __shared__ float Ws[64][67];
    __shared__ u64 red[32][16];
    const int tid = threadIdx.x;
    const int tb = blockIdx.x >> 4;   // 0..15
    const int tn = blockIdx.x & 15;   // 0..15
    const int b0 = tb * 32, n0 = tn * 64;
    const int ty = tid >> 4, tx = tid & 15;

    float acc[2][4];
#pragma unroll
    for (int i = 0; i < 2; ++i)
#pragma unroll
        for (int j = 0; j < 4; ++j) acc[i][j] = 0.f;

    for (int kc = 0; kc < E; kc += 64) {
        const int c4 = tx * 4;
#pragma unroll
        for (int s = 0; s < 2; ++s) {
            const int r = ty + 16 * s;
            float4 zv = *(const float4*)(Zg + (size_t)(b0 + r) * E + kc + c4);
            Zs[r][c4 + 0] = zv.x; Zs[r][c4 + 1] = zv.y;
            Zs[r][c4 + 2] = zv.z; Zs[r][c4 + 3] = zv.w;
        }
#pragma unroll
        for (int s = 0; s < 4; ++s) {
            const int r = ty + 16 * s;
            float4 wv = *(const float4*)(Wg + (size_t)(n0 + r) * E + kc + c4);
            Ws[r][c4 + 0] = wv.x; Ws[r][c4 + 1] = wv.y;
            Ws[r][c4 + 2] = wv.z; Ws[r][c4 + 3] = wv.w;
        }
        __syncthreads();
#pragma unroll 4
        for (int k = 0; k < 64; ++k) {
            float zr[2], wr[4];
#pragma unroll
            for (int i = 0; i < 2; ++i) zr[i] = Zs[ty * 2 + i][k];
#pragma unroll
            for (int j = 0; j < 4; ++j) wr[j] = Ws[tx * 4 + j][k];
#pragma unroll
            for (int i = 0; i < 2; ++i)
#pragma unroll
                for (int j = 0; j < 4; ++j) {
                    float d = zr[i] - wr[j];
                    acc[i][j] = fmaf(d, d, acc[i][j]);
                }
        }
        __syncthreads();
    }
#pragma unroll
    for (int i = 0; i < 2; ++i) {
        float best = acc[i][0];
        int bj = 0;
#pragma unroll
        for (int j = 1; j < 4; ++j)
            if (acc[i][j] < best) { best = acc[i][j]; bj = j; }
        red[ty * 2 + i][tx] = ((u64)__float_as_uint(best) << 32) |
                              (unsigned)(n0 + tx * 4 + bj);
    }
    __syncthreads();
    if (tid < 32) {
        u64 m = red[tid][0];
#pragma unroll
        for (int t = 1; t < 16; ++t) {
            const u64 v = red[tid][t];
            if (v < m) m = v;
        }
        bmupart[(size_t)tn * B + b0 + tid] = m;
    }
}

// K2: reduce bmu candidates + h[b, hw] = eta * exp(-lattice_d2 / (2 sigma^2))
__global__ __launch_bounds__(256) void h_kernel(const u64* __restrict__ bmupart,
                                                const int* __restrict__ step,
                                                float* __restrict__ h) {
    const int b = blockIdx.x;
    u64 m = bmupart[b];
#pragma unroll
    for (int tn = 1; tn < 16; ++tn) {
        const u64 v = bmupart[(size_t)tn * B + b];
        if (v < m) m = v;
    }
    const int u = (int)(m & 0xffffffffULL);
    const int ur = u >> 5, uc = u & 31;
    const float n = (float)step[0];
    const float decay = expf(-n * 0.01f);
    const float eta = 0.3f * decay;
    const float sigma = 16.0f * decay;
    const float inv2s2 = 1.0f / (2.0f * sigma * sigma);
#pragma unroll
    for (int s = 0; s < 4; ++s) {
        const int t = threadIdx.x + s * 256;
        const int i = t >> 5, j = t & 31;
        const float dr = (float)(ur - i), dc = (float)(uc - j);
        h[(size_t)b * L + t] = eta * expf(-(dr * dr + dc * dc) * inv2s2);
    }
}

// ---------------------------------------------------------------------------
// K3 mega: blocks 0..1023 -> SOM update; blocks 1024.. -> delta writer.
// R8-proven EXACT form. Do not touch.
// ---------------------------------------------------------------------------
__global__ __launch_bounds__(256) void delta_update_kernel(const float* __restrict__ Zg,
                                                           const float* __restrict__ Wg,
                                                           const float* __restrict__ h,
                                                           float* __restrict__ somn,
                                                           float* __restrict__ delta) {
    if (blockIdx.x < 1024) {
        const int hw = blockIdx.x;
        const int e = threadIdx.x;
        float acc = 0.f, hsum = 0.f;
#pragma unroll 8
        for (int b = 0; b < B; ++b) {
            const float hv = h[(size_t)b * L + hw];
            acc = fmaf(hv, Zg[(size_t)b * E + e], acc);
            hsum += hv;
        }
        const float w = Wg[(size_t)hw * E + e];
        somn[(size_t)hw * E + e] = w + (1.0f / (float)B) * (acc - hsum * w);
        return;
    }
    const int bid = blockIdx.x - 1024;       // 512 * 256 blocks
    const int b = bid >> 8;
    const int hw = ((bid & 255) << 2) + (threadIdx.x >> 6);
    const int lane = threadIdx.x & 63;
    const float hs = h[(size_t)b * L + hw];
    const float4 z = *(const float4*)(Zg + (size_t)b * E + lane * 4);
    const float4 w = *(const float4*)(Wg + (size_t)hw * E + lane * 4);
    f32x4 o;
    o.x = hs * (z.x - w.x);
    o.y = hs * (z.y - w.y);
    o.z = hs * (z.z - w.z);
    o.w = hs * (z.w - w.w);
    __builtin_nontemporal_store(o, (f32x4*)(delta + ((size_t)b * L + hw) * E + lane * 4));
}

// ---------------------------------------------------------------------------
// K4: raw_q = 1/(1+dist(Z, SOM_new)) + fixed-order row partials.
// Same 32x64 re-tile as K1 (256 blocks).
// ---------------------------------------------------------------------------
__global__ __launch_bounds__(256) void distq_kernel(const float* __restrict__ Zg,
                                                    const float* __restrict__ Wg,
                                                    float* __restrict__ out,
                                                    float* __restrict__ part_rs) {
    __shared__ float Zs[32][67];
    __shared__ float Ws[64][67];
    __shared__ float red[32][16];
    const int tid = threadIdx.x;
    const int tb = blockIdx.x >> 4;   // 0..15
    const int tn = blockIdx.x & 15;   // 0..15
    const int b0 = tb * 32, n0 = tn * 64;
    const int ty = tid >> 4, tx = tid & 15;

    float acc[2][4];
#pragma unroll
    for (int i = 0; i < 2; ++i)
#pragma unroll
        for (int j = 0; j < 4; ++j) acc[i][j] = 0.f;

    for (int kc = 0; kc < E; kc += 64) {
        const int c4 = tx * 4;
#pragma unroll
        for (int s = 0; s < 2; ++s) {
            const int r = ty + 16 * s;
            float4 zv = *(const float4*)(Zg + (size_t)(b0 + r) * E + kc + c4);
            Zs[r][c4 + 0] = zv.x; Zs[r][c4 + 1] = zv.y;
            Zs[r][c4 + 2] = zv.z; Zs[r][c4 + 3] = zv.w;
        }
#pragma unroll
        for (int s = 0; s < 4; ++s) {
            const int r = ty + 16 * s;
            float4 wv = *(const float4*)(Wg + (size_t)(n0 + r) * E + kc + c4);
            Ws[r][c4 + 0] = wv.x; Ws[r][c4 + 1] = wv.y;
            Ws[r][c4 + 2] = wv.z; Ws[r][c4 + 3] = wv.w;
        }
        __syncthreads();
#pragma unroll 4
        for (int k = 0; k < 64; ++k) {
            float zr[2], wr[4];
#pragma unroll
            for (int i = 0; i < 2; ++i) zr[i] = Zs[ty * 2 + i][k];
#pragma unroll
            for (int j = 0; j < 4; ++j) wr[j] = Ws[tx * 4 + j][k];
#pragma unroll
            for (int i = 0; i < 2; ++i)
#pragma unroll
                for (int j = 0; j < 4; ++j) {
                    float d = zr[i] - wr[j];
                    acc[i][j] = fmaf(d, d, acc[i][j]);
                }
        }
        __syncthreads();
    }
#pragma unroll
    for (int i = 0; i < 2; ++i) {
        const int b = b0 + ty * 2 + i;
        float4 v;
        v.x = 1.f / (1.f + sqrtf(acc[i][0]));
        v.y = 1.f / (1.f + sqrtf(acc[i][1]));
        v.z = 1.f / (1.f + sqrtf(acc[i][2]));
        v.w = 1.f / (1.f + sqrtf(acc[i][3]));
        *(float4*)(out + (size_t)b * L + n0 + tx * 4) = v;
        red[ty * 2 + i][tx] = v.x + v.y + v.z + v.w;   // fixed order within thread
    }
    __syncthreads();
    if (tid < 32) {
        float s = red[tid][0];
#pragma unroll
        for (int t = 1; t < 16; ++t) s += red[tid][t];  // ascending tx = ascending j
        part_rs[(size_t)tn * B + b0 + tid] = s;
    }
}

// K5: colsum partials with inline irs: part[c][j] = sum_{b in chunk} q[b][j]*irs[b]
__global__ __launch_bounds__(256) void colsum_part_kernel(const float* __restrict__ q,
                                                          const float* __restrict__ prs,
                                                          float* __restrict__ part) {
    __shared__ float sirs[32];
    const int j = (blockIdx.x & 3) * 256 + threadIdx.x;
    const int c = blockIdx.x >> 2;   // 0..15
    const int b0 = c * 32;
    if (threadIdx.x < 32) {
        float s = 0.f;
#pragma unroll
        for (int tn = 0; tn < 16; ++tn) s += prs[(size_t)tn * B + b0 + threadIdx.x];
        sirs[threadIdx.x] = 1.0f / s;
    }
    __syncthreads();
    float acc = 0.f;
#pragma unroll 8
    for (int bo = 0; bo < 32; ++bo)
        acc = fmaf(q[(size_t)(b0 + bo) * L + j], sirs[bo], acc);
    part[(size_t)c * L + j] = acc;
}

// K6: kl[b] = T/S - log(S); irs[b] and cs[j] computed inline (fixed order).
__global__ __launch_bounds__(256) void kl_kernel(const float* __restrict__ q,
                                                 const float* __restrict__ prs,
                                                 const float* __restrict__ part,
                                                 float* __restrict__ kl) {
    const int b = blockIdx.x;
    const int tid = threadIdx.x;
    float rs = 0.f;
#pragma unroll
    for (int tn = 0; tn < 16; ++tn) rs += prs[(size_t)tn * B + b];  // uniform -> broadcast
    const float irsb = 1.0f / rs;
    float S = 0.f, T = 0.f;
#pragma unroll
    for (int s = 0; s < 4; ++s) {
        const int j = tid + s * 256;
        float csj = 0.f;
#pragma unroll
        for (int c = 0; c < 16; ++c) csj += part[(size_t)c * L + j];
        const float qq = q[(size_t)b * L + j] * irsb;
        const float ic = 1.0f / csj;
        const float rp = qq * qq * ic;
        S += rp;
        T = fmaf(rp, logf(qq * ic), T);
    }
    __shared__ float sS[256], sT[256];
    sS[tid] = S; sT[tid] = T;
    __syncthreads();
    for (int st = 128; st > 0; st >>= 1) {
        if (tid < st) { sS[tid] += sS[tid + st]; sT[tid] += sT[tid + st]; }
        __syncthreads();
    }
    if (tid == 0) kl[b] = sT[0] / sS[0] - logf(sS[0]);
}

extern "C" void kernel_launch(void* const* d_in, const int* in_sizes, int n_in,
                              void* d_out, int out_size, void* d_ws, size_t ws_size,
                              hipStream_t stream) {
    const float* Zg = (const float*)d_in[0];
    const float* Wg = (const float*)d_in[1];
    const int* step = (const int*)d_in[2];
    float* out = (float*)d_out;          // [0,512): kl_loss, [512,...): delta
    float* ws = (float*)d_ws;

    float* q    = ws + O_Q;
    float* somn = ws + O_SOMN;
    float* part = ws + O_PART;
    float* prs  = ws + O_PRS;
    float* h    = ws + O_H;
    u64*   bmup = (u64*)(ws + O_BMUP);

    float* kl    = out;
    float* delta = out + B;

    hipLaunchKernelGGL(dist_bmu_kernel, dim3(256), dim3(256), 0, stream, Zg, Wg, bmup);
    hipLaunchKernelGGL(h_kernel, dim3(B), dim3(256), 0, stream, bmup, step, h);
    hipLaunchKernelGGL(delta_update_kernel, dim3(1024 + B * 256), dim3(256), 0, stream,
                       Zg, Wg, h, somn, delta);
    hipLaunchKernelGGL(distq_kernel, dim3(256), dim3(256), 0, stream, Zg, somn, q, prs);
    hipLaunchKernelGGL(colsum_part_kernel, dim3(64), dim3(256), 0, stream, q, prs, part);
    hipLaunchKernelGGL(kl_kernel, dim3(B), dim3(256), 0, stream, q, prs, part, kl);
}

// Round 13
// 118.668 us; speedup vs baseline: 1.8140x; 1.1197x over previous
//
#include <hip/hip_runtime.h>
#include <math.h>

// Problem constants
#define B 512
#define E 256
#define L 1024  // 32*32

typedef float f32x4 __attribute__((ext_vector_type(4)));
typedef unsigned long long u64;

// Workspace layout (floats)
#define O_Q     0u           // B*L   raw_q
#define O_SOMN  524288u      // L*E
#define O_PART  786432u      // 16*L  colsum partials
#define O_PRS   802816u      // 16*B  rowsum partials (from distq)
#define O_H     811008u      // B*L   eta-scaled h
#define O_BMUP  1335296u     // 16*B u64 packed per-tile argmin candidates

// ---------------------------------------------------------------------------
// Shared delta body (R5/R8/R12-proven): one 16B NT store per thread.
// b = bbase + (bid>>8), bid local to the delta region of the grid.
// ---------------------------------------------------------------------------
__device__ __forceinline__ void delta_body(int bid, int bbase, int tid,
                                           const float* __restrict__ Zg,
                                           const float* __restrict__ Wg,
                                           const float* __restrict__ h,
                                           float* __restrict__ delta) {
    const int b = bbase + (bid >> 8);
    const int hw = ((bid & 255) << 2) + (tid >> 6);
    const int lane = tid & 63;
    const float hs = h[(size_t)b * L + hw];
    const float4 z = *(const float4*)(Zg + (size_t)b * E + lane * 4);
    const float4 w = *(const float4*)(Wg + (size_t)hw * E + lane * 4);
    f32x4 o;
    o.x = hs * (z.x - w.x);
    o.y = hs * (z.y - w.y);
    o.z = hs * (z.z - w.z);
    o.w = hs * (z.w - w.w);
    __builtin_nontemporal_store(o, (f32x4*)(delta + ((size_t)b * L + hw) * E + lane * 4));
}

// ---------------------------------------------------------------------------
// K1: dist^2(Z, SOM) fused argmin -> bmupart[tn][b]  (R12-proven, 256 blocks)
// ---------------------------------------------------------------------------
__global__ __launch_bounds__(256) void dist_bmu_kernel(const float* __restrict__ Zg,
                                                       const float* __restrict__ Wg,
                                                       u64* __restrict__ bmupart) {
    __shared__ float Zs[32][67];
    __shared__ float Ws[64][67];
    __shared__ u64 red[32][16];
    const int tid = threadIdx.x;
    const int tb = blockIdx.x >> 4;   // 0..15
    const int tn = blockIdx.x & 15;   // 0..15
    const int b0 = tb * 32, n0 = tn * 64;
    const int ty = tid >> 4, tx = tid & 15;

    float acc[2][4];
#pragma unroll
    for (int i = 0; i < 2; ++i)
#pragma unroll
        for (int j = 0; j < 4; ++j) acc[i][j] = 0.f;

    for (int kc = 0; kc < E; kc += 64) {
        const int c4 = tx * 4;
#pragma unroll
        for (int s = 0; s < 2; ++s) {
            const int r = ty + 16 * s;
            float4 zv = *(const float4*)(Zg + (size_t)(b0 + r) * E + kc + c4);
            Zs[r][c4 + 0] = zv.x; Zs[r][c4 + 1] = zv.y;
            Zs[r][c4 + 2] = zv.z; Zs[r][c4 + 3] = zv.w;
        }
#pragma unroll
        for (int s = 0; s < 4; ++s) {
            const int r = ty + 16 * s;
            float4 wv = *(const float4*)(Wg + (size_t)(n0 + r) * E + kc + c4);
            Ws[r][c4 + 0] = wv.x; Ws[r][c4 + 1] = wv.y;
            Ws[r][c4 + 2] = wv.z; Ws[r][c4 + 3] = wv.w;
        }
        __syncthreads();
#pragma unroll 4
        for (int k = 0; k < 64; ++k) {
            float zr[2], wr[4];
#pragma unroll
            for (int i = 0; i < 2; ++i) zr[i] = Zs[ty * 2 + i][k];
#pragma unroll
            for (int j = 0; j < 4; ++j) wr[j] = Ws[tx * 4 + j][k];
#pragma unroll
            for (int i = 0; i < 2; ++i)
#pragma unroll
                for (int j = 0; j < 4; ++j) {
                    float d = zr[i] - wr[j];
                    acc[i][j] = fmaf(d, d, acc[i][j]);
                }
        }
        __syncthreads();
    }
#pragma unroll
    for (int i = 0; i < 2; ++i) {
        float best = acc[i][0];
        int bj = 0;
#pragma unroll
        for (int j = 1; j < 4; ++j)
            if (acc[i][j] < best) { best = acc[i][j]; bj = j; }
        red[ty * 2 + i][tx] = ((u64)__float_as_uint(best) << 32) |
                              (unsigned)(n0 + tx * 4 + bj);
    }
    __syncthreads();
    if (tid < 32) {
        u64 m = red[tid][0];
#pragma unroll
        for (int t = 1; t < 16; ++t) {
            const u64 v = red[tid][t];
            if (v < m) m = v;
        }
        bmupart[(size_t)tn * B + b0 + tid] = m;
    }
}

// K2: reduce bmu candidates + h row write (R12-proven)
__global__ __launch_bounds__(256) void h_kernel(const u64* __restrict__ bmupart,
                                                const int* __restrict__ step,
                                                float* __restrict__ h) {
    const int b = blockIdx.x;
    u64 m = bmupart[b];
#pragma unroll
    for (int tn = 1; tn < 16; ++tn) {
        const u64 v = bmupart[(size_t)tn * B + b];
        if (v < m) m = v;
    }
    const int u = (int)(m & 0xffffffffULL);
    const int ur = u >> 5, uc = u & 31;
    const float n = (float)step[0];
    const float decay = expf(-n * 0.01f);
    const float eta = 0.3f * decay;
    const float sigma = 16.0f * decay;
    const float inv2s2 = 1.0f / (2.0f * sigma * sigma);
#pragma unroll
    for (int s = 0; s < 4; ++s) {
        const int t = threadIdx.x + s * 256;
        const int i = t >> 5, j = t & 31;
        const float dr = (float)(ur - i), dc = (float)(uc - j);
        h[(size_t)b * L + t] = eta * expf(-(dr * dr + dc * dc) * inv2s2);
    }
}

// ---------------------------------------------------------------------------
// K3 mega1: blocks 0..1023 -> SOM update; rest -> delta b in [0,384).
// ---------------------------------------------------------------------------
__global__ __launch_bounds__(256) void mega1_kernel(const float* __restrict__ Zg,
                                                    const float* __restrict__ Wg,
                                                    const float* __restrict__ h,
                                                    float* __restrict__ somn,
                                                    float* __restrict__ delta) {
    if (blockIdx.x < 1024) {
        const int hw = blockIdx.x;
        const int e = threadIdx.x;
        float acc = 0.f, hsum = 0.f;
#pragma unroll 8
        for (int b = 0; b < B; ++b) {
            const float hv = h[(size_t)b * L + hw];
            acc = fmaf(hv, Zg[(size_t)b * E + e], acc);
            hsum += hv;
        }
        const float w = Wg[(size_t)hw * E + e];
        somn[(size_t)hw * E + e] = w + (1.0f / (float)B) * (acc - hsum * w);
        return;
    }
    delta_body(blockIdx.x - 1024, 0, threadIdx.x, Zg, Wg, h, delta);
}

// ---------------------------------------------------------------------------
// K4 mega2: blocks 0..255 -> distq (raw_q + row partials); rest -> delta
// b in [384,448). distq body identical to R12 (shared aliased from one pool).
// ---------------------------------------------------------------------------
__global__ __launch_bounds__(256) void mega2_kernel(const float* __restrict__ Zg,
                                                    const float* __restrict__ Wg,     // SOM (for delta)
                                                    const float* __restrict__ somn,   // SOM_new (for distq)
                                                    const float* __restrict__ h,
                                                    float* __restrict__ q,
                                                    float* __restrict__ prs,
                                                    float* __restrict__ delta) {
    __shared__ float smem[32 * 67 + 64 * 67 + 32 * 16];
    if (blockIdx.x < 256) {
        float(*Zs)[67] = (float(*)[67])smem;
        float(*Ws)[67] = (float(*)[67])(smem + 32 * 67);
        float(*red)[16] = (float(*)[16])(smem + 32 * 67 + 64 * 67);
        const int tid = threadIdx.x;
        const int tb = blockIdx.x >> 4;   // 0..15
        const int tn = blockIdx.x & 15;   // 0..15
        const int b0 = tb * 32, n0 = tn * 64;
        const int ty = tid >> 4, tx = tid & 15;

        float acc[2][4];
#pragma unroll
        for (int i = 0; i < 2; ++i)
#pragma unroll
            for (int j = 0; j < 4; ++j) acc[i][j] = 0.f;

        for (int kc = 0; kc < E; kc += 64) {
            const int c4 = tx * 4;
#pragma unroll
            for (int s = 0; s < 2; ++s) {
                const int r = ty + 16 * s;
                float4 zv = *(const float4*)(Zg + (size_t)(b0 + r) * E + kc + c4);
                Zs[r][c4 + 0] = zv.x; Zs[r][c4 + 1] = zv.y;
                Zs[r][c4 + 2] = zv.z; Zs[r][c4 + 3] = zv.w;
            }
#pragma unroll
            for (int s = 0; s < 4; ++s) {
                const int r = ty + 16 * s;
                float4 wv = *(const float4*)(somn + (size_t)(n0 + r) * E + kc + c4);
                Ws[r][c4 + 0] = wv.x; Ws[r][c4 + 1] = wv.y;
                Ws[r][c4 + 2] = wv.z; Ws[r][c4 + 3] = wv.w;
            }
            __syncthreads();
#pragma unroll 4
            for (int k = 0; k < 64; ++k) {
                float zr[2], wr[4];
#pragma unroll
                for (int i = 0; i < 2; ++i) zr[i] = Zs[ty * 2 + i][k];
#pragma unroll
                for (int j = 0; j < 4; ++j) wr[j] = Ws[tx * 4 + j][k];
#pragma unroll
                for (int i = 0; i < 2; ++i)
#pragma unroll
                    for (int j = 0; j < 4; ++j) {
                        float d = zr[i] - wr[j];
                        acc[i][j] = fmaf(d, d, acc[i][j]);
                    }
            }
            __syncthreads();
        }
#pragma unroll
        for (int i = 0; i < 2; ++i) {
            const int b = b0 + ty * 2 + i;
            float4 v;
            v.x = 1.f / (1.f + sqrtf(acc[i][0]));
            v.y = 1.f / (1.f + sqrtf(acc[i][1]));
            v.z = 1.f / (1.f + sqrtf(acc[i][2]));
            v.w = 1.f / (1.f + sqrtf(acc[i][3]));
            *(float4*)(q + (size_t)b * L + n0 + tx * 4) = v;
            red[ty * 2 + i][tx] = v.x + v.y + v.z + v.w;   // fixed order
        }
        __syncthreads();
        if (tid < 32) {
            float s = red[tid][0];
#pragma unroll
            for (int t = 1; t < 16; ++t) s += red[tid][t];  // ascending tx
            prs[(size_t)tn * B + b0 + tid] = s;
        }
        return;
    }
    delta_body(blockIdx.x - 256, 384, threadIdx.x, Zg, Wg, h, delta);
}

// ---------------------------------------------------------------------------
// K5 mega3: blocks 0..63 -> colsum partials (inline irs); rest -> delta
// b in [448,480).
// ---------------------------------------------------------------------------
__global__ __launch_bounds__(256) void mega3_kernel(const float* __restrict__ Zg,
                                                    const float* __restrict__ Wg,
                                                    const float* __restrict__ h,
                                                    const float* __restrict__ q,
                                                    const float* __restrict__ prs,
                                                    float* __restrict__ part,
                                                    float* __restrict__ delta) {
    if (blockIdx.x < 64) {
        __shared__ float sirs[32];
        const int j = (blockIdx.x & 3) * 256 + threadIdx.x;
        const int c = blockIdx.x >> 2;   // 0..15
        const int b0 = c * 32;
        if (threadIdx.x < 32) {
            float s = 0.f;
#pragma unroll
            for (int tn = 0; tn < 16; ++tn) s += prs[(size_t)tn * B + b0 + threadIdx.x];
            sirs[threadIdx.x] = 1.0f / s;
        }
        __syncthreads();
        float acc = 0.f;
#pragma unroll 8
        for (int bo = 0; bo < 32; ++bo)
            acc = fmaf(q[(size_t)(b0 + bo) * L + j], sirs[bo], acc);
        part[(size_t)c * L + j] = acc;
        return;
    }
    delta_body(blockIdx.x - 64, 448, threadIdx.x, Zg, Wg, h, delta);
}

// ---------------------------------------------------------------------------
// K6 mega4: blocks 0..511 -> KL; rest -> delta b in [480,512).
// ---------------------------------------------------------------------------
__global__ __launch_bounds__(256) void mega4_kernel(const float* __restrict__ Zg,
                                                    const float* __restrict__ Wg,
                                                    const float* __restrict__ h,
                                                    const float* __restrict__ q,
                                                    const float* __restrict__ prs,
                                                    const float* __restrict__ part,
                                                    float* __restrict__ kl,
                                                    float* __restrict__ delta) {
    if (blockIdx.x < 512) {
        __shared__ float sS[256], sT[256];
        const int b = blockIdx.x;
        const int tid = threadIdx.x;
        float rs = 0.f;
#pragma unroll
        for (int tn = 0; tn < 16; ++tn) rs += prs[(size_t)tn * B + b];
        const float irsb = 1.0f / rs;
        float S = 0.f, T = 0.f;
#pragma unroll
        for (int s = 0; s < 4; ++s) {
            const int j = tid + s * 256;
            float csj = 0.f;
#pragma unroll
            for (int c = 0; c < 16; ++c) csj += part[(size_t)c * L + j];
            const float qq = q[(size_t)b * L + j] * irsb;
            const float ic = 1.0f / csj;
            const float rp = qq * qq * ic;
            S += rp;
            T = fmaf(rp, logf(qq * ic), T);
        }
        sS[tid] = S; sT[tid] = T;
        __syncthreads();
        for (int st = 128; st > 0; st >>= 1) {
            if (tid < st) { sS[tid] += sS[tid + st]; sT[tid] += sT[tid + st]; }
            __syncthreads();
        }
        if (tid == 0) kl[b] = sT[0] / sS[0] - logf(sS[0]);
        return;
    }
    delta_body(blockIdx.x - 512, 480, threadIdx.x, Zg, Wg, h, delta);
}

extern "C" void kernel_launch(void* const* d_in, const int* in_sizes, int n_in,
                              void* d_out, int out_size, void* d_ws, size_t ws_size,
                              hipStream_t stream) {
    const float* Zg = (const float*)d_in[0];
    const float* Wg = (const float*)d_in[1];
    const int* step = (const int*)d_in[2];
    float* out = (float*)d_out;          // [0,512): kl_loss, [512,...): delta
    float* ws = (float*)d_ws;

    float* q    = ws + O_Q;
    float* somn = ws + O_SOMN;
    float* part = ws + O_PART;
    float* prs  = ws + O_PRS;
    float* h    = ws + O_H;
    u64*   bmup = (u64*)(ws + O_BMUP);

    float* kl    = out;
    float* delta = out + B;

    hipLaunchKernelGGL(dist_bmu_kernel, dim3(256), dim3(256), 0, stream, Zg, Wg, bmup);
    hipLaunchKernelGGL(h_kernel, dim3(B), dim3(256), 0, stream, bmup, step, h);
    hipLaunchKernelGGL(mega1_kernel, dim3(1024 + 384 * 256), dim3(256), 0, stream,
                       Zg, Wg, h, somn, delta);
    hipLaunchKernelGGL(mega2_kernel, dim3(256 + 64 * 256), dim3(256), 0, stream,
                       Zg, Wg, somn, h, q, prs, delta);
    hipLaunchKernelGGL(mega3_kernel, dim3(64 + 32 * 256), dim3(256), 0, stream,
                       Zg, Wg, h, q, prs, part, delta);
    hipLaunchKernelGGL(mega4_kernel, dim3(512 + 32 * 256), dim3(256), 0, stream,
                       Zg, Wg, h, q, prs, part, kl, delta);
}